// Round 4
// baseline (245.483 us; speedup 1.0000x reference)
//
#include <hip/hip_runtime.h>
#include <hip/hip_bf16.h>

typedef unsigned short u16;
typedef unsigned int u32;
using bf16x8 = __attribute__((ext_vector_type(8))) short;  // 8 bf16 (4 VGPRs)
using f32x4  = __attribute__((ext_vector_type(4))) float;  // 4 fp32

#define BB 512
#define TT 256
#define CC 192
#define HH 64

__device__ __forceinline__ u16 f2bf(float f) {
    __hip_bfloat16 h = __float2bfloat16(f);   // RNE
    u16 u; __builtin_memcpy(&u, &h, 2); return u;
}

// ================= prep kernels =================

// W_sw: B-fragment-swizzled weights. Frag fid = n3*6+ks (n3 = mat*4 + ntile, ks = K-step).
// lane (quad,l15) element u  =  W[c = ks*32+quad*8+u][h = (n3&3)*16+l15] of matrix n3>>2.
__global__ void wprep_kernel(const float* __restrict__ Wq,
                             const float* __restrict__ Wk,
                             const float* __restrict__ Wv,
                             u16* __restrict__ W_sw) {
    int gid  = blockIdx.x * 256 + threadIdx.x;   // 0..4607 (72 frags * 64 lanes)
    int fid  = gid >> 6, lane = gid & 63;
    int n3   = fid / 6,  ks   = fid % 6;
    int l15  = lane & 15, quad = lane >> 4;
    const float* W = (n3 < 4) ? Wq : (n3 < 8) ? Wk : Wv;
    const int h = (n3 & 3) * 16 + l15;
    u16* dst = W_sw + (size_t)gid * 8;
    #pragma unroll
    for (int u = 0; u < 8; ++u) {
        int c = ks * 32 + quad * 8 + u;
        dst[u] = f2bf(W[c * HH + h]);
    }
}

// poskT[h][t], posqT[h][t]
__global__ void pos_kernel(const float* __restrict__ Wk,
                           const float* __restrict__ Wq,
                           const float* __restrict__ pe,
                           float* __restrict__ poskT, float* __restrict__ posqT) {
    int t = blockIdx.x * 4 + (threadIdx.x >> 6);   // grid 64 x 256
    int h = threadIdx.x & 63;
    float ak = 0.f, aq = 0.f;
    for (int c = 0; c < CC; ++c) {
        float p = pe[t * CC + c];             // group-uniform broadcast
        ak += p * Wk[c * HH + h];             // coalesced
        aq += p * Wq[c * HH + h];
    }
    poskT[h * TT + t] = ak;
    posqT[h * TT + t] = aq;
}

// bias in C/D-fragment layout: bias_sw[(i*16+jt)*64 + lane] = float4 over r,
// component r = bias[row t0+quad*4+r][col jt*16+l15]  (only jt<=i written/read)
__global__ void bias_kernel(const float* __restrict__ poskT,
                            const float* __restrict__ posqT,
                            float4* __restrict__ bias_sw) {
    const int i = blockIdx.x >> 4, jt = blockIdx.x & 15;
    if (jt > i) return;
    const int lane = threadIdx.x;
    const int l15 = lane & 15, quad = lane >> 4;
    const int tq = i * 16 + quad * 4;     // query rows tq..tq+3
    const int jc = jt * 16 + l15;         // key col
    float s[4] = {0.f, 0.f, 0.f, 0.f};
    for (int h = 0; h < HH; ++h) {
        float pq = posqT[h * TT + jc];
        #pragma unroll
        for (int r = 0; r < 4; ++r)
            s[r] += poskT[h * TT + tq + r] * pq;
    }
    bias_sw[blockIdx.x * 64 + lane] = make_float4(s[0], s[1], s[2], s[3]);
}

// ================= kernel 1: QKV projection GEMM (no LDS, no barrier) =========
// grid 2048: block = (b = blk>>2, rb = blk&3) covers rows rb*64..+63 of batch b.
// v3: X A-fragments loaded DIRECTLY from global into registers — the frag
// pattern (row m*16+l15, 32B at col ks*32+quad*8) is a clean 16-segment
// global_load_dwordx4 pair. All 4 waves read identical X addresses -> L1
// broadcast serves 3/4. No LDS, no __syncthreads, no vmcnt(0) drain: each
// wave self-paces, compiler pipelines the 48 independent loads against MFMAs.
// W fragments (18 = 72 VGPR) hoisted first (L2-resident after block 0).

__global__ __launch_bounds__(256, 3)
void qkv_kernel(const float* __restrict__ x,
                const u16* __restrict__ W_sw,
                u16* __restrict__ q_sw, u16* __restrict__ k_sw,
                u16* __restrict__ vg) {
    const int tid  = threadIdx.x;
    const int w    = tid >> 6;
    const int lane = tid & 63;
    const int l15  = lane & 15;
    const int quad = lane >> 4;
    const int b    = blockIdx.x >> 2;
    const int rb   = blockIdx.x & 3;
    const float* xb = x + ((size_t)b * TT + rb * 64) * CC;   // 64 contiguous rows

    // ---- hoist W fragments for this wave's h-tile ----
    const bf16x8* Wv8 = (const bf16x8*)W_sw;
    bf16x8 Wf[18];                              // [mat][ks], mat: 0=Q 1=K 2=V
    #pragma unroll
    for (int mat = 0; mat < 3; ++mat)
        #pragma unroll
        for (int ks = 0; ks < 6; ++ks)
            Wf[mat * 6 + ks] = Wv8[(((mat * 4 + w) * 6) + ks) * 64 + lane];

    // ---- MFMA: wave w computes h-tile w of Q,K,V for all 4 m-tiles ----
    f32x4 acc[12];                              // [m][mat] = acc[m*3+mat]
    #pragma unroll
    for (int i = 0; i < 12; ++i) acc[i] = {0.f, 0.f, 0.f, 0.f};
    #pragma unroll
    for (int ks = 0; ks < 6; ++ks) {
        bf16x8 a[4];
        #pragma unroll
        for (int m = 0; m < 4; ++m) {
            const float* p = xb + (m * 16 + l15) * CC + ks * 32 + quad * 8;
            const float4 f0 = *(const float4*)(p);
            const float4 f1 = *(const float4*)(p + 4);
            bf16x8 av;
            av[0] = (short)f2bf(f0.x); av[1] = (short)f2bf(f0.y);
            av[2] = (short)f2bf(f0.z); av[3] = (short)f2bf(f0.w);
            av[4] = (short)f2bf(f1.x); av[5] = (short)f2bf(f1.y);
            av[6] = (short)f2bf(f1.z); av[7] = (short)f2bf(f1.w);
            a[m] = av;
        }
        #pragma unroll
        for (int m = 0; m < 4; ++m)
            #pragma unroll
            for (int mat = 0; mat < 3; ++mat)
                acc[m * 3 + mat] = __builtin_amdgcn_mfma_f32_16x16x32_bf16(
                    a[m], Wf[mat * 6 + ks], acc[m * 3 + mat], 0, 0, 0);
    }

    // ---- epilogue: h-tile index is w ----
    const int hs    = w >> 1;
    const int quadp = (w * 2 + (l15 >> 3)) & 3;
    const int u     = l15 & 7;
    #pragma unroll
    for (int m = 0; m < 4; ++m) {
        const int i_loc  = rb * 4 + m;                 // t-tile within batch (0..15)
        const size_t bi  = (size_t)b * 16 + i_loc;
        const size_t base = (bi * 2 + hs) * 512 + (quadp * 16 + quad * 4) * 8 + u;
        #pragma unroll
        for (int r = 0; r < 4; ++r) {
            q_sw[base + r * 8] = f2bf(acc[m * 3 + 0][r]);   // Q -> A-frag layout
            k_sw[base + r * 8] = f2bf(acc[m * 3 + 1][r]);   // K -> B-frag layout
        }
        const size_t t_glob = (size_t)b * TT + i_loc * 16;
        #pragma unroll
        for (int r = 0; r < 4; ++r)
            vg[(t_glob + quad * 4 + r) * HH + w * 16 + l15] = f2bf(acc[m * 3 + 2][r]);
    }
}

// ================= kernel 2: lean flash attention (R1 version, unchanged) =====
// LDS: Vt[64][264] + per-wave P[16][40] = 38,912 B -> 4 blocks/CU.
// grid 1024 (2 blocks/batch); wave tile sets balanced to SumJ = 17 each.
#define VP 264
#define PP 40
#define VT_ELEMS (HH * VP)               // 16896
#define P_ELEMS 640                      // 16*40
#define LDSB_ELEMS (VT_ELEMS + 4 * P_ELEMS)

__global__ __launch_bounds__(256, 4)
void attn_kernel(const u16* __restrict__ q_sw, const u16* __restrict__ k_sw,
                 const u16* __restrict__ vg, const float4* __restrict__ bias_sw,
                 float* __restrict__ out) {
    __shared__ __align__(16) u16 lds[LDSB_ELEMS];
    const int tid  = threadIdx.x;
    const int w    = tid >> 6;
    const int lane = tid & 63;
    const int l15  = lane & 15;
    const int quad = lane >> 4;
    const int b    = blockIdx.x >> 1;
    const int half = blockIdx.x & 1;

    // ---- stage V^T: thread tid handles key-row j = tid ----
    {
        const u16* vrow = vg + ((size_t)b * TT + tid) * HH;
        #pragma unroll
        for (int u2 = 0; u2 < 8; ++u2) {
            bf16x8 vv = *(const bf16x8*)(vrow + u2 * 8);
            #pragma unroll
            for (int e = 0; e < 8; ++e)
                lds[(u2 * 8 + e) * VP + tid] = (u16)vv[e];
        }
    }
    __syncthreads();

    u16* Pw = &lds[VT_ELEMS + w * P_ELEMS];
    const float scale = 0.07216878364870322f;  // 192^-0.5
    const f32x4 zero4 = {0.f, 0.f, 0.f, 0.f};
    const bf16x8* qv = (const bf16x8*)q_sw;
    const bf16x8* kv = (const bf16x8*)k_sw;

    #pragma unroll 1
    for (int mt = 0; mt < 2; ++mt) {
        // balanced causal tile sets: half0 w: {w, 15-w}; half1 w: {4+w, 11-w}
        const int i  = half ? (mt ? 11 - w : 4 + w) : (mt ? 15 - w : w);
        const int t0 = 16 * i;
        const int J  = i + 1;
        const int Pq = (J + 1) >> 1;
        const size_t bi = (size_t)b * 16 + i;

        const bf16x8 qf0 = qv[(bi * 2 + 0) * 64 + lane];   // coalesced 1KB
        const bf16x8 qf1 = qv[(bi * 2 + 1) * 64 + lane];

        f32x4 o[4];
        float m4[4], l4[4];
        #pragma unroll
        for (int n = 0; n < 4; ++n) o[n] = zero4;
        #pragma unroll
        for (int r = 0; r < 4; ++r) { m4[r] = -1e30f; l4[r] = 0.f; }

        #pragma unroll
        for (int p = 0; p < 8; ++p) {
            if (p < Pq) {
                const int jt0 = 2 * p, jt1 = 2 * p + 1;
                // ---- S tiles (pair), all loads coalesced ----
                f32x4 sa = zero4, sb;
                {
                    const size_t bj = (size_t)b * 16 + jt0;
                    bf16x8 k0 = kv[(bj * 2 + 0) * 64 + lane];
                    bf16x8 k1 = kv[(bj * 2 + 1) * 64 + lane];
                    sa = __builtin_amdgcn_mfma_f32_16x16x32_bf16(qf0, k0, sa, 0, 0, 0);
                    sa = __builtin_amdgcn_mfma_f32_16x16x32_bf16(qf1, k1, sa, 0, 0, 0);
                    const float4 b4 = bias_sw[(i * 16 + jt0) * 64 + lane];
                    sa[0] = sa[0] * scale + b4.x;
                    sa[1] = sa[1] * scale + b4.y;
                    sa[2] = sa[2] * scale + b4.z;
                    sa[3] = sa[3] * scale + b4.w;
                    if (jt0 == i) {
                        #pragma unroll
                        for (int r = 0; r < 4; ++r)
                            if (l15 > quad * 4 + r) sa[r] = -1e30f;
                    }
                }
                if (jt1 < J) {
                    sb = zero4;
                    const size_t bj = (size_t)b * 16 + jt1;
                    bf16x8 k0 = kv[(bj * 2 + 0) * 64 + lane];
                    bf16x8 k1 = kv[(bj * 2 + 1) * 64 + lane];
                    sb = __builtin_amdgcn_mfma_f32_16x16x32_bf16(qf0, k0, sb, 0, 0, 0);
                    sb = __builtin_amdgcn_mfma_f32_16x16x32_bf16(qf1, k1, sb, 0, 0, 0);
                    const float4 b4 = bias_sw[(i * 16 + jt1) * 64 + lane];
                    sb[0] = sb[0] * scale + b4.x;
                    sb[1] = sb[1] * scale + b4.y;
                    sb[2] = sb[2] * scale + b4.z;
                    sb[3] = sb[3] * scale + b4.w;
                    if (jt1 == i) {
                        #pragma unroll
                        for (int r = 0; r < 4; ++r)
                            if (l15 > quad * 4 + r) sb[r] = -1e30f;
                    }
                } else {
                    sb[0] = -1e30f; sb[1] = -1e30f; sb[2] = -1e30f; sb[3] = -1e30f;
                }
                // ---- pair row max (16-lane group shares rows) ----
                float t4[4];
                #pragma unroll
                for (int r = 0; r < 4; ++r) t4[r] = fmaxf(sa[r], sb[r]);
                #pragma unroll
                for (int d = 1; d < 16; d <<= 1) {
                    #pragma unroll
                    for (int r = 0; r < 4; ++r) t4[r] = fmaxf(t4[r], __shfl_xor(t4[r], d, 64));
                }
                // ---- online rescale ----
                float al[4];
                #pragma unroll
                for (int r = 0; r < 4; ++r) {
                    float mn = fmaxf(m4[r], t4[r]);
                    al[r] = __expf(m4[r] - mn);   // first pair: exp(-huge)=0
                    m4[r] = mn;
                    l4[r] *= al[r];
                }
                #pragma unroll
                for (int n = 0; n < 4; ++n)
                #pragma unroll
                for (int r = 0; r < 4; ++r) o[n][r] *= al[r];
                // ---- exp + P -> per-wave LDS ----
                #pragma unroll
                for (int r = 0; r < 4; ++r) {
                    float e0 = __expf(sa[r] - m4[r]);
                    float e1 = __expf(sb[r] - m4[r]);   // invalid tile -> exp(-huge)=0
                    l4[r] += e0 + e1;                   // per-lane partial, reduced later
                    Pw[(quad * 4 + r) * PP + l15]      = f2bf(e0);
                    Pw[(quad * 4 + r) * PP + 16 + l15] = f2bf(e1);
                }
                // ---- PV ----
                bf16x8 pa = *(const bf16x8*)&Pw[l15 * PP + quad * 8];
                #pragma unroll
                for (int n = 0; n < 4; ++n) {
                    bf16x8 bv = *(const bf16x8*)&lds[(n * 16 + l15) * VP + p * 32 + quad * 8];
                    o[n] = __builtin_amdgcn_mfma_f32_16x16x32_bf16(pa, bv, o[n], 0, 0, 0);
                }
            }
        }
        // ---- row-sum reduce + normalize + store ----
        #pragma unroll
        for (int d = 1; d < 16; d <<= 1) {
            #pragma unroll
            for (int r = 0; r < 4; ++r) l4[r] += __shfl_xor(l4[r], d, 64);
        }
        float rl4[4];
        #pragma unroll
        for (int r = 0; r < 4; ++r) rl4[r] = 1.f / l4[r];
        float* ob = out + ((size_t)b * TT + t0) * HH;
        #pragma unroll
        for (int n = 0; n < 4; ++n)
        #pragma unroll
        for (int r = 0; r < 4; ++r)
            ob[(quad * 4 + r) * HH + n * 16 + l15] = o[n][r] * rl4[r];
    }
}

extern "C" void kernel_launch(void* const* d_in, const int* in_sizes, int n_in,
                              void* d_out, int out_size, void* d_ws, size_t ws_size,
                              hipStream_t stream) {
    const float* x  = (const float*)d_in[0];
    const float* Wk = (const float*)d_in[1];
    const float* Wq = (const float*)d_in[2];
    const float* Wv = (const float*)d_in[3];
    const float* pe = (const float*)d_in[4];
    float* out = (float*)d_out;

    // ws: poskT[16384]f | posqT[16384]f | bias_sw[16384]float4-elems(f) | W_sw[36864]u16
    //     | q_sw | k_sw | vg   (bf16, 16 MB each)
    float*  poskT  = (float*)d_ws;
    float*  posqT  = poskT + TT * HH;
    float4* biassw = (float4*)(posqT + TT * HH);
    u16*    W_sw   = (u16*)((float*)biassw + TT * TT);
    u16*    q_sw   = W_sw + 3 * HH * CC;
    u16*    k_sw   = q_sw + (size_t)BB * TT * HH;
    u16*    vg     = k_sw + (size_t)BB * TT * HH;

    wprep_kernel<<<18, 256, 0, stream>>>(Wq, Wk, Wv, W_sw);
    pos_kernel<<<TT / 4, 256, 0, stream>>>(Wk, Wq, pe, poskT, posqT);
    bias_kernel<<<256, 64, 0, stream>>>(poskT, posqT, biassw);
    qkv_kernel<<<4 * BB, 256, 0, stream>>>(x, W_sw, q_sw, k_sw, vg);
    attn_kernel<<<2 * BB, 256, 0, stream>>>(q_sw, k_sw, vg, biassw, out);
}

// Round 7
// 216.004 us; speedup vs baseline: 1.1365x; 1.1365x over previous
//
#include <hip/hip_runtime.h>
#include <hip/hip_bf16.h>

typedef unsigned short u16;
typedef unsigned int u32;
using bf16x8 = __attribute__((ext_vector_type(8))) short;  // 8 bf16 (4 VGPRs)
using f32x4  = __attribute__((ext_vector_type(4))) float;  // 4 fp32

#define BB 512
#define TT 256
#define CC 192
#define HH 64

__device__ __forceinline__ u16 f2bf(float f) {
    __hip_bfloat16 h = __float2bfloat16(f);   // RNE
    u16 u; __builtin_memcpy(&u, &h, 2); return u;
}

// ================= prep kernels (unchanged) =================

// W_sw: B-fragment-swizzled weights. Frag fid = n3*6+ks (n3 = mat*4 + ntile, ks = K-step).
// lane (quad,l15) element u  =  W[c = ks*32+quad*8+u][h = (n3&3)*16+l15] of matrix n3>>2.
__global__ void wprep_kernel(const float* __restrict__ Wq,
                             const float* __restrict__ Wk,
                             const float* __restrict__ Wv,
                             u16* __restrict__ W_sw) {
    int gid  = blockIdx.x * 256 + threadIdx.x;   // 0..4607 (72 frags * 64 lanes)
    int fid  = gid >> 6, lane = gid & 63;
    int n3   = fid / 6,  ks   = fid % 6;
    int l15  = lane & 15, quad = lane >> 4;
    const float* W = (n3 < 4) ? Wq : (n3 < 8) ? Wk : Wv;
    const int h = (n3 & 3) * 16 + l15;
    u16* dst = W_sw + (size_t)gid * 8;
    #pragma unroll
    for (int u = 0; u < 8; ++u) {
        int c = ks * 32 + quad * 8 + u;
        dst[u] = f2bf(W[c * HH + h]);
    }
}

// poskT[h][t], posqT[h][t]
__global__ void pos_kernel(const float* __restrict__ Wk,
                           const float* __restrict__ Wq,
                           const float* __restrict__ pe,
                           float* __restrict__ poskT, float* __restrict__ posqT) {
    int t = blockIdx.x * 4 + (threadIdx.x >> 6);   // grid 64 x 256
    int h = threadIdx.x & 63;
    float ak = 0.f, aq = 0.f;
    for (int c = 0; c < CC; ++c) {
        float p = pe[t * CC + c];             // group-uniform broadcast
        ak += p * Wk[c * HH + h];             // coalesced
        aq += p * Wq[c * HH + h];
    }
    poskT[h * TT + t] = ak;
    posqT[h * TT + t] = aq;
}

// bias in C/D-fragment layout: bias_sw[(i*16+jt)*64 + lane] = float4 over r,
// component r = bias[row t0+quad*4+r][col jt*16+l15]  (only jt<=i written/read)
__global__ void bias_kernel(const float* __restrict__ poskT,
                            const float* __restrict__ posqT,
                            float4* __restrict__ bias_sw) {
    const int i = blockIdx.x >> 4, jt = blockIdx.x & 15;
    if (jt > i) return;
    const int lane = threadIdx.x;
    const int l15 = lane & 15, quad = lane >> 4;
    const int tq = i * 16 + quad * 4;     // query rows tq..tq+3
    const int jc = jt * 16 + l15;         // key col
    float s[4] = {0.f, 0.f, 0.f, 0.f};
    for (int h = 0; h < HH; ++h) {
        float pq = posqT[h * TT + jc];
        #pragma unroll
        for (int r = 0; r < 4; ++r)
            s[r] += poskT[h * TT + tq + r] * pq;
    }
    bias_sw[blockIdx.x * 64 + lane] = make_float4(s[0], s[1], s[2], s[3]);
}

// ================= fused kernel: QKV projection + flash attention ============
// One block per batch (grid 512, 256 threads). DYNAMIC LDS 112,128 B
// (extern __shared__ + hipFuncSetAttribute — the proven >64K route on gfx950;
// static >64K was the prime suspect in the R5/R6 container failures).
// Phase 1: 8 chunks of 32 rows. X staged bf16 via R0's PROVEN register-staging
// pack (float4 load -> pack -> ds_write, XP=200 pitch). Wave w computes h-tile
// w of Q,K,V; W frags hoisted, protected from sinking only by sched_barrier(0)
// (compile-time, cannot fault) + the 1-wave/SIMD VGPR budget.
// Q,K fragments and V^T go to LDS (exact old q_sw/k_sw/vg layouts), removing
// the 150 MB HBM intermediate round-trip.
// Phase 2: R1's proven attention body; q/k/v reads become ds_reads.
// Wave w owns causal i-tiles {w, 15-w, 4+w, 11-w} (SumJ = 34 for all waves).

#define XP 200                           // X pitch (u16); 400 B rows, 16B-aligned
#define VP 264
#define PP 40
#define P_ELEMS 640                      // 16*40 u16 per wave
// LDS byte map (all offsets 16B-aligned):
//   [0,     12800)  X stage (32 rows x XP u16 bf16)   /  P in phase 2 (5120 B)
//   [12800, 45568)  Q frags  (16 tiles x 2 x 1024 B)
//   [45568, 78336)  K frags
//   [78336,112128)  V^T      (64 x VP u16)
#define Q_OFF 12800
#define K_OFF 45568
#define V_OFF 78336
#define LDS_TOTAL 112128

__global__ __launch_bounds__(256, 1)
void fused_kernel(const float* __restrict__ x,
                  const u16* __restrict__ W_sw,
                  const float4* __restrict__ bias_sw,
                  float* __restrict__ out) {
    extern __shared__ __align__(16) char smem[];
    u16* xs   = (u16*)smem;
    u16* Qlds = (u16*)(smem + Q_OFF);
    u16* Klds = (u16*)(smem + K_OFF);
    u16* Vt   = (u16*)(smem + V_OFF);

    const int tid  = threadIdx.x;
    const int w    = tid >> 6;
    const int lane = tid & 63;
    const int l15  = lane & 15;
    const int quad = lane >> 4;
    const int b    = blockIdx.x;

    // ---- hoist W fragments for this wave's h-tile ----
    const bf16x8* Wv8 = (const bf16x8*)W_sw;
    bf16x8 Wf[18];                              // [mat][ks], mat: 0=Q 1=K 2=V
    #pragma unroll
    for (int mat = 0; mat < 3; ++mat)
        #pragma unroll
        for (int ks = 0; ks < 6; ++ks)
            Wf[mat * 6 + ks] = Wv8[(((mat * 4 + w) * 6) + ks) * 64 + lane];
    __builtin_amdgcn_sched_barrier(0);   // compile-time fence: W loads stay here

    // ================= phase 1: projection (8 chunks x 32 rows) =============
    const int hs    = w >> 1;
    const int quadp = (w * 2 + (l15 >> 3)) & 3;
    const int uu    = l15 & 7;

    #pragma unroll 1
    for (int c8 = 0; c8 < 8; ++c8) {
        const float* xb = x + ((size_t)b * TT + c8 * 32) * CC;
        // stage X chunk -> LDS bf16 (R0's proven coalesced pack: 6 float4/thread)
        #pragma unroll
        for (int it = 0; it < 6; ++it) {
            const int flat = (it * 256 + tid) * 4;       // 0..6143
            const int row = flat / CC, col = flat % CC;  // CC%4==0: no row cross
            const float4 v = *(const float4*)(xb + flat);
            uint2 pk;
            pk.x = (u32)f2bf(v.x) | ((u32)f2bf(v.y) << 16);
            pk.y = (u32)f2bf(v.z) | ((u32)f2bf(v.w) << 16);
            *(uint2*)&xs[row * XP + col] = pk;
        }
        __syncthreads();   // X visible to all waves

        f32x4 acc[6];                           // [m][mat] = acc[m*3+mat], m=0..1
        #pragma unroll
        for (int i = 0; i < 6; ++i) acc[i] = {0.f, 0.f, 0.f, 0.f};
        #pragma unroll
        for (int ks = 0; ks < 6; ++ks) {
            bf16x8 a[2];
            #pragma unroll
            for (int m = 0; m < 2; ++m)
                a[m] = *(const bf16x8*)&xs[(m * 16 + l15) * XP + ks * 32 + quad * 8];
            #pragma unroll
            for (int m = 0; m < 2; ++m)
                #pragma unroll
                for (int mat = 0; mat < 3; ++mat)
                    acc[m * 3 + mat] = __builtin_amdgcn_mfma_f32_16x16x32_bf16(
                        a[m], Wf[mat * 6 + ks], acc[m * 3 + mat], 0, 0, 0);
        }

        // epilogue: Q/K frags + V^T into LDS (same layouts as old globals)
        #pragma unroll
        for (int m = 0; m < 2; ++m) {
            const int i_loc = c8 * 2 + m;                  // t-tile 0..15
            const int base  = (i_loc * 2 + hs) * 512 + (quadp * 16 + quad * 4) * 8 + uu;
            #pragma unroll
            for (int r = 0; r < 4; ++r) {
                Qlds[base + r * 8] = f2bf(acc[m * 3 + 0][r]);   // A-frag layout
                Klds[base + r * 8] = f2bf(acc[m * 3 + 1][r]);   // B-frag layout
            }
            #pragma unroll
            for (int r = 0; r < 4; ++r)
                Vt[(w * 16 + l15) * VP + i_loc * 16 + quad * 4 + r]
                    = f2bf(acc[m * 3 + 2][r]);                  // V^T[h][t]
        }
        __syncthreads();   // X readers done (next chunk overwrites); last iter
    }                      // doubles as the proj->attn barrier

    // ================= phase 2: attention =================
    u16* Pw = (u16*)smem + w * P_ELEMS;         // X region is dead now
    const float scale = 0.07216878364870322f;  // 192^-0.5
    const f32x4 zero4 = {0.f, 0.f, 0.f, 0.f};
    const bf16x8* qv = (const bf16x8*)Qlds;
    const bf16x8* kv = (const bf16x8*)Klds;

    #pragma unroll 1
    for (int mt = 0; mt < 4; ++mt) {
        // balanced causal sets: {w, 15-w, 4+w, 11-w}, SumJ = 34 per wave
        const int i = (mt == 0) ? w : (mt == 1) ? 15 - w : (mt == 2) ? 4 + w : 11 - w;
        const int t0 = 16 * i;
        const int J  = i + 1;
        const int Pq = (J + 1) >> 1;

        const bf16x8 qf0 = qv[(i * 2 + 0) * 64 + lane];
        const bf16x8 qf1 = qv[(i * 2 + 1) * 64 + lane];

        f32x4 o[4];
        float m4[4], l4[4];
        #pragma unroll
        for (int n = 0; n < 4; ++n) o[n] = zero4;
        #pragma unroll
        for (int r = 0; r < 4; ++r) { m4[r] = -1e30f; l4[r] = 0.f; }

        #pragma unroll
        for (int p = 0; p < 8; ++p) {
            if (p < Pq) {
                const int jt0 = 2 * p, jt1 = 2 * p + 1;
                // ---- S tiles (pair) ----
                f32x4 sa = zero4, sb;
                {
                    bf16x8 k0 = kv[(jt0 * 2 + 0) * 64 + lane];
                    bf16x8 k1 = kv[(jt0 * 2 + 1) * 64 + lane];
                    sa = __builtin_amdgcn_mfma_f32_16x16x32_bf16(qf0, k0, sa, 0, 0, 0);
                    sa = __builtin_amdgcn_mfma_f32_16x16x32_bf16(qf1, k1, sa, 0, 0, 0);
                    const float4 b4 = bias_sw[(i * 16 + jt0) * 64 + lane];
                    sa[0] = sa[0] * scale + b4.x;
                    sa[1] = sa[1] * scale + b4.y;
                    sa[2] = sa[2] * scale + b4.z;
                    sa[3] = sa[3] * scale + b4.w;
                    if (jt0 == i) {
                        #pragma unroll
                        for (int r = 0; r < 4; ++r)
                            if (l15 > quad * 4 + r) sa[r] = -1e30f;
                    }
                }
                if (jt1 < J) {
                    sb = zero4;
                    bf16x8 k0 = kv[(jt1 * 2 + 0) * 64 + lane];
                    bf16x8 k1 = kv[(jt1 * 2 + 1) * 64 + lane];
                    sb = __builtin_amdgcn_mfma_f32_16x16x32_bf16(qf0, k0, sb, 0, 0, 0);
                    sb = __builtin_amdgcn_mfma_f32_16x16x32_bf16(qf1, k1, sb, 0, 0, 0);
                    const float4 b4 = bias_sw[(i * 16 + jt1) * 64 + lane];
                    sb[0] = sb[0] * scale + b4.x;
                    sb[1] = sb[1] * scale + b4.y;
                    sb[2] = sb[2] * scale + b4.z;
                    sb[3] = sb[3] * scale + b4.w;
                    if (jt1 == i) {
                        #pragma unroll
                        for (int r = 0; r < 4; ++r)
                            if (l15 > quad * 4 + r) sb[r] = -1e30f;
                    }
                } else {
                    sb[0] = -1e30f; sb[1] = -1e30f; sb[2] = -1e30f; sb[3] = -1e30f;
                }
                // ---- pair row max (16-lane group shares rows) ----
                float t4[4];
                #pragma unroll
                for (int r = 0; r < 4; ++r) t4[r] = fmaxf(sa[r], sb[r]);
                #pragma unroll
                for (int d = 1; d < 16; d <<= 1) {
                    #pragma unroll
                    for (int r = 0; r < 4; ++r) t4[r] = fmaxf(t4[r], __shfl_xor(t4[r], d, 64));
                }
                // ---- online rescale ----
                float al[4];
                #pragma unroll
                for (int r = 0; r < 4; ++r) {
                    float mn = fmaxf(m4[r], t4[r]);
                    al[r] = __expf(m4[r] - mn);   // first pair: exp(-huge)=0
                    m4[r] = mn;
                    l4[r] *= al[r];
                }
                #pragma unroll
                for (int n = 0; n < 4; ++n)
                #pragma unroll
                for (int r = 0; r < 4; ++r) o[n][r] *= al[r];
                // ---- exp + P -> per-wave LDS ----
                #pragma unroll
                for (int r = 0; r < 4; ++r) {
                    float e0 = __expf(sa[r] - m4[r]);
                    float e1 = __expf(sb[r] - m4[r]);   // invalid tile -> 0
                    l4[r] += e0 + e1;
                    Pw[(quad * 4 + r) * PP + l15]      = f2bf(e0);
                    Pw[(quad * 4 + r) * PP + 16 + l15] = f2bf(e1);
                }
                // ---- PV ----
                bf16x8 pa = *(const bf16x8*)&Pw[l15 * PP + quad * 8];
                #pragma unroll
                for (int n = 0; n < 4; ++n) {
                    bf16x8 bv = *(const bf16x8*)&Vt[(n * 16 + l15) * VP + p * 32 + quad * 8];
                    o[n] = __builtin_amdgcn_mfma_f32_16x16x32_bf16(pa, bv, o[n], 0, 0, 0);
                }
            }
        }
        // ---- row-sum reduce + normalize + store ----
        #pragma unroll
        for (int d = 1; d < 16; d <<= 1) {
            #pragma unroll
            for (int r = 0; r < 4; ++r) l4[r] += __shfl_xor(l4[r], d, 64);
        }
        float rl4[4];
        #pragma unroll
        for (int r = 0; r < 4; ++r) rl4[r] = 1.f / l4[r];
        float* ob = out + ((size_t)b * TT + t0) * HH;
        #pragma unroll
        for (int n = 0; n < 4; ++n)
        #pragma unroll
        for (int r = 0; r < 4; ++r)
            ob[(quad * 4 + r) * HH + n * 16 + l15] = o[n][r] * rl4[r];
    }
}

extern "C" void kernel_launch(void* const* d_in, const int* in_sizes, int n_in,
                              void* d_out, int out_size, void* d_ws, size_t ws_size,
                              hipStream_t stream) {
    const float* x  = (const float*)d_in[0];
    const float* Wk = (const float*)d_in[1];
    const float* Wq = (const float*)d_in[2];
    const float* Wv = (const float*)d_in[3];
    const float* pe = (const float*)d_in[4];
    float* out = (float*)d_out;

    // ws: poskT[16384]f | posqT[16384]f | bias_sw[16384]float4-elems | W_sw[36864]u16
    float*  poskT  = (float*)d_ws;
    float*  posqT  = poskT + TT * HH;
    float4* biassw = (float4*)(posqT + TT * HH);
    u16*    W_sw   = (u16*)((float*)biassw + TT * TT);

    // one-time opt-in for >64K dynamic LDS (host-side, not a stream op;
    // not in the graph-capture forbidden list)
    static bool attr_set = false;
    if (!attr_set) {
        hipFuncSetAttribute(reinterpret_cast<const void*>(fused_kernel),
                            hipFuncAttributeMaxDynamicSharedMemorySize, LDS_TOTAL);
        attr_set = true;
    }

    wprep_kernel<<<18, 256, 0, stream>>>(Wq, Wk, Wv, W_sw);
    pos_kernel<<<TT / 4, 256, 0, stream>>>(Wk, Wq, pe, poskT, posqT);
    bias_kernel<<<256, 64, 0, stream>>>(poskT, posqT, biassw);
    fused_kernel<<<BB, 256, LDS_TOTAL, stream>>>(x, W_sw, biassw, out);
}

// Round 8
// 201.078 us; speedup vs baseline: 1.2208x; 1.0742x over previous
//
#include <hip/hip_runtime.h>
#include <hip/hip_bf16.h>

typedef unsigned short u16;
typedef unsigned int u32;
using bf16x8 = __attribute__((ext_vector_type(8))) short;  // 8 bf16 (4 VGPRs)
using f32x4  = __attribute__((ext_vector_type(4))) float;  // 4 fp32

#define BB 512
#define TT 256
#define CC 192
#define HH 64

__device__ __forceinline__ u16 f2bf(float f) {
    __hip_bfloat16 h = __float2bfloat16(f);   // RNE
    u16 u; __builtin_memcpy(&u, &h, 2); return u;
}

// ================= prep kernels (unchanged) =================

// W_sw: B-fragment-swizzled weights. Frag fid = n3*6+ks (n3 = mat*4 + ntile, ks = K-step).
// lane (quad,l15) element u  =  W[c = ks*32+quad*8+u][h = (n3&3)*16+l15] of matrix n3>>2.
__global__ void wprep_kernel(const float* __restrict__ Wq,
                             const float* __restrict__ Wk,
                             const float* __restrict__ Wv,
                             u16* __restrict__ W_sw) {
    int gid  = blockIdx.x * 256 + threadIdx.x;   // 0..4607 (72 frags * 64 lanes)
    int fid  = gid >> 6, lane = gid & 63;
    int n3   = fid / 6,  ks   = fid % 6;
    int l15  = lane & 15, quad = lane >> 4;
    const float* W = (n3 < 4) ? Wq : (n3 < 8) ? Wk : Wv;
    const int h = (n3 & 3) * 16 + l15;
    u16* dst = W_sw + (size_t)gid * 8;
    #pragma unroll
    for (int u = 0; u < 8; ++u) {
        int c = ks * 32 + quad * 8 + u;
        dst[u] = f2bf(W[c * HH + h]);
    }
}

// poskT[h][t], posqT[h][t]
__global__ void pos_kernel(const float* __restrict__ Wk,
                           const float* __restrict__ Wq,
                           const float* __restrict__ pe,
                           float* __restrict__ poskT, float* __restrict__ posqT) {
    int t = blockIdx.x * 4 + (threadIdx.x >> 6);   // grid 64 x 256
    int h = threadIdx.x & 63;
    float ak = 0.f, aq = 0.f;
    for (int c = 0; c < CC; ++c) {
        float p = pe[t * CC + c];             // group-uniform broadcast
        ak += p * Wk[c * HH + h];             // coalesced
        aq += p * Wq[c * HH + h];
    }
    poskT[h * TT + t] = ak;
    posqT[h * TT + t] = aq;
}

// bias in C/D-fragment layout: bias_sw[(i*16+jt)*64 + lane] = float4 over r,
// component r = bias[row t0+quad*4+r][col jt*16+l15]  (only jt<=i written/read)
__global__ void bias_kernel(const float* __restrict__ poskT,
                            const float* __restrict__ posqT,
                            float4* __restrict__ bias_sw) {
    const int i = blockIdx.x >> 4, jt = blockIdx.x & 15;
    if (jt > i) return;
    const int lane = threadIdx.x;
    const int l15 = lane & 15, quad = lane >> 4;
    const int tq = i * 16 + quad * 4;     // query rows tq..tq+3
    const int jc = jt * 16 + l15;         // key col
    float s[4] = {0.f, 0.f, 0.f, 0.f};
    for (int h = 0; h < HH; ++h) {
        float pq = posqT[h * TT + jc];
        #pragma unroll
        for (int r = 0; r < 4; ++r)
            s[r] += poskT[h * TT + tq + r] * pq;
    }
    bias_sw[blockIdx.x * 64 + lane] = make_float4(s[0], s[1], s[2], s[3]);
}

// ================= fused kernel: QKV projection + flash attention ============
// v2 of the fused design: 512 threads (8 waves -> 2/SIMD), dynamic LDS
// 124,928 B, X double-buffered.
// Phase 1: 8 chunks x 32 rows. Wave (mh=w>>2, w4=w&3) computes m-tile mh,
// h-tile w4 of Q,K,V (18 MFMA/chunk, acc[3]). Chunk c+1's global loads issue
// BEFORE chunk c's MFMAs; ds_write lands after -> HBM latency hidden (T14).
// One barrier per chunk. W frags (18 = 72 VGPR) hoisted and PINNED via
// asm "+v" keep-alive (defeats the remat/sink seen in R7: VGPR=80).
// Phase 2: R1's proven attention body; wave w owns i-tiles {w, 15-w}
// (SumJ=17/wave, 34/SIMD balanced). P buffer lives in the dead X region.

#define XP 200                           // X pitch (u16); 400 B rows
#define VP 264
#define PP 40
#define P_ELEMS 640                      // 16*40 u16 per wave
#define XBUF 12800                       // bytes per X buffer (32 rows x 400 B)
// LDS byte map (16B-aligned):
//   [0,      25600)  X dbuf (2 x 12800)   /  P in phase 2 (8 x 1280 B)
//   [25600,  58368)  Q frags  (16 tiles x 2 x 1024 B)
//   [58368,  91136)  K frags
//   [91136, 124928)  V^T      (64 x VP u16)
#define Q_OFF 25600
#define K_OFF 58368
#define V_OFF 91136
#define LDS_TOTAL 124928

__global__ __launch_bounds__(512, 1)
void fused_kernel(const float* __restrict__ x,
                  const u16* __restrict__ W_sw,
                  const float4* __restrict__ bias_sw,
                  float* __restrict__ out) {
    extern __shared__ __align__(16) char smem[];
    u16* Qlds = (u16*)(smem + Q_OFF);
    u16* Klds = (u16*)(smem + K_OFF);
    u16* Vt   = (u16*)(smem + V_OFF);

    const int tid  = threadIdx.x;
    const int w    = tid >> 6;           // 0..7
    const int w4   = w & 3;              // h-tile
    const int mh   = w >> 2;             // m-tile within 32-row chunk
    const int lane = tid & 63;
    const int l15  = lane & 15;
    const int quad = lane >> 4;
    const int b    = blockIdx.x;

    // ---- hoist W fragments for h-tile w4, pin them in registers ----
    const bf16x8* Wv8 = (const bf16x8*)W_sw;
    bf16x8 Wf[18];                              // [mat][ks], mat: 0=Q 1=K 2=V
    #pragma unroll
    for (int mat = 0; mat < 3; ++mat)
        #pragma unroll
        for (int ks = 0; ks < 6; ++ks)
            Wf[mat * 6 + ks] = Wv8[(((mat * 4 + w4) * 6) + ks) * 64 + lane];
    #pragma unroll
    for (int j = 0; j < 18; ++j)
        asm volatile("" : "+v"(Wf[j]));         // output constraint kills remat

    // ================= phase 1: projection (8 chunks x 32 rows, X dbuf) =====
    const int hs    = w4 >> 1;
    const int quadp = (w4 * 2 + (l15 >> 3)) & 3;
    const int uu    = l15 & 7;

    // prologue: stage chunk 0 into buf 0
    {
        const float* xb = x + (size_t)b * TT * CC;
        float4 vv[3];
        #pragma unroll
        for (int it = 0; it < 3; ++it)
            vv[it] = *(const float4*)(xb + (it * 512 + tid) * 4);
        u16* xs = (u16*)smem;
        #pragma unroll
        for (int it = 0; it < 3; ++it) {
            const int flat = (it * 512 + tid) * 4;
            const int row = flat / CC, col = flat % CC;   // CC%4==0: no row cross
            uint2 pk;
            pk.x = (u32)f2bf(vv[it].x) | ((u32)f2bf(vv[it].y) << 16);
            pk.y = (u32)f2bf(vv[it].z) | ((u32)f2bf(vv[it].w) << 16);
            *(uint2*)&xs[row * XP + col] = pk;
        }
    }
    __syncthreads();

    #pragma unroll 1
    for (int c8 = 0; c8 < 8; ++c8) {
        const int cur = c8 & 1;
        // ---- issue next chunk's global loads FIRST (hide under MFMAs) ----
        float4 vnext[3];
        if (c8 < 7) {
            const float* xb = x + ((size_t)b * TT + (c8 + 1) * 32) * CC;
            #pragma unroll
            for (int it = 0; it < 3; ++it)
                vnext[it] = *(const float4*)(xb + (it * 512 + tid) * 4);
        }
        // ---- compute from buf[cur] ----
        const u16* xs = (const u16*)(smem + cur * XBUF);
        f32x4 acc[3];
        #pragma unroll
        for (int i = 0; i < 3; ++i) acc[i] = {0.f, 0.f, 0.f, 0.f};
        #pragma unroll
        for (int ks = 0; ks < 6; ++ks) {
            const bf16x8 a = *(const bf16x8*)&xs[(mh * 16 + l15) * XP + ks * 32 + quad * 8];
            #pragma unroll
            for (int mat = 0; mat < 3; ++mat)
                acc[mat] = __builtin_amdgcn_mfma_f32_16x16x32_bf16(
                    a, Wf[mat * 6 + ks], acc[mat], 0, 0, 0);
        }
        // ---- epilogue: Q/K frags + V^T into LDS ----
        {
            const int i_loc = c8 * 2 + mh;                 // t-tile 0..15
            const int base  = (i_loc * 2 + hs) * 512 + (quadp * 16 + quad * 4) * 8 + uu;
            #pragma unroll
            for (int r = 0; r < 4; ++r) {
                Qlds[base + r * 8] = f2bf(acc[0][r]);      // A-frag layout
                Klds[base + r * 8] = f2bf(acc[1][r]);      // B-frag layout
            }
            #pragma unroll
            for (int r = 0; r < 4; ++r)
                Vt[(w4 * 16 + l15) * VP + i_loc * 16 + quad * 4 + r]
                    = f2bf(acc[2][r]);                     // V^T[h][t]
        }
        // ---- write next chunk into the other buffer (safe: its readers
        //      finished before the previous barrier) ----
        if (c8 < 7) {
            u16* xsn = (u16*)(smem + (1 - cur) * XBUF);
            #pragma unroll
            for (int it = 0; it < 3; ++it) {
                const int flat = (it * 512 + tid) * 4;
                const int row = flat / CC, col = flat % CC;
                uint2 pk;
                pk.x = (u32)f2bf(vnext[it].x) | ((u32)f2bf(vnext[it].y) << 16);
                pk.y = (u32)f2bf(vnext[it].z) | ((u32)f2bf(vnext[it].w) << 16);
                *(uint2*)&xsn[row * XP + col] = pk;
            }
        }
        __syncthreads();   // buf[cur] readers done; epilogue/next-buf visible
    }

    // ================= phase 2: attention =================
    u16* Pw = (u16*)smem + w * P_ELEMS;         // X region is dead now
    const float scale = 0.07216878364870322f;  // 192^-0.5
    const f32x4 zero4 = {0.f, 0.f, 0.f, 0.f};
    const bf16x8* qv = (const bf16x8*)Qlds;
    const bf16x8* kv = (const bf16x8*)Klds;

    #pragma unroll 1
    for (int mt = 0; mt < 2; ++mt) {
        // balanced causal sets: wave w owns {w, 15-w}; SumJ = 17 per wave
        const int i  = mt ? 15 - w : w;
        const int t0 = 16 * i;
        const int J  = i + 1;
        const int Pq = (J + 1) >> 1;

        const bf16x8 qf0 = qv[(i * 2 + 0) * 64 + lane];
        const bf16x8 qf1 = qv[(i * 2 + 1) * 64 + lane];

        f32x4 o[4];
        float m4[4], l4[4];
        #pragma unroll
        for (int n = 0; n < 4; ++n) o[n] = zero4;
        #pragma unroll
        for (int r = 0; r < 4; ++r) { m4[r] = -1e30f; l4[r] = 0.f; }

        #pragma unroll
        for (int p = 0; p < 8; ++p) {
            if (p < Pq) {
                const int jt0 = 2 * p, jt1 = 2 * p + 1;
                // ---- S tiles (pair) ----
                f32x4 sa = zero4, sb;
                {
                    bf16x8 k0 = kv[(jt0 * 2 + 0) * 64 + lane];
                    bf16x8 k1 = kv[(jt0 * 2 + 1) * 64 + lane];
                    sa = __builtin_amdgcn_mfma_f32_16x16x32_bf16(qf0, k0, sa, 0, 0, 0);
                    sa = __builtin_amdgcn_mfma_f32_16x16x32_bf16(qf1, k1, sa, 0, 0, 0);
                    const float4 b4 = bias_sw[(i * 16 + jt0) * 64 + lane];
                    sa[0] = sa[0] * scale + b4.x;
                    sa[1] = sa[1] * scale + b4.y;
                    sa[2] = sa[2] * scale + b4.z;
                    sa[3] = sa[3] * scale + b4.w;
                    if (jt0 == i) {
                        #pragma unroll
                        for (int r = 0; r < 4; ++r)
                            if (l15 > quad * 4 + r) sa[r] = -1e30f;
                    }
                }
                if (jt1 < J) {
                    sb = zero4;
                    bf16x8 k0 = kv[(jt1 * 2 + 0) * 64 + lane];
                    bf16x8 k1 = kv[(jt1 * 2 + 1) * 64 + lane];
                    sb = __builtin_amdgcn_mfma_f32_16x16x32_bf16(qf0, k0, sb, 0, 0, 0);
                    sb = __builtin_amdgcn_mfma_f32_16x16x32_bf16(qf1, k1, sb, 0, 0, 0);
                    const float4 b4 = bias_sw[(i * 16 + jt1) * 64 + lane];
                    sb[0] = sb[0] * scale + b4.x;
                    sb[1] = sb[1] * scale + b4.y;
                    sb[2] = sb[2] * scale + b4.z;
                    sb[3] = sb[3] * scale + b4.w;
                    if (jt1 == i) {
                        #pragma unroll
                        for (int r = 0; r < 4; ++r)
                            if (l15 > quad * 4 + r) sb[r] = -1e30f;
                    }
                } else {
                    sb[0] = -1e30f; sb[1] = -1e30f; sb[2] = -1e30f; sb[3] = -1e30f;
                }
                // ---- pair row max (16-lane group shares rows) ----
                float t4[4];
                #pragma unroll
                for (int r = 0; r < 4; ++r) t4[r] = fmaxf(sa[r], sb[r]);
                #pragma unroll
                for (int d = 1; d < 16; d <<= 1) {
                    #pragma unroll
                    for (int r = 0; r < 4; ++r) t4[r] = fmaxf(t4[r], __shfl_xor(t4[r], d, 64));
                }
                // ---- online rescale ----
                float al[4];
                #pragma unroll
                for (int r = 0; r < 4; ++r) {
                    float mn = fmaxf(m4[r], t4[r]);
                    al[r] = __expf(m4[r] - mn);   // first pair: exp(-huge)=0
                    m4[r] = mn;
                    l4[r] *= al[r];
                }
                #pragma unroll
                for (int n = 0; n < 4; ++n)
                #pragma unroll
                for (int r = 0; r < 4; ++r) o[n][r] *= al[r];
                // ---- exp + P -> per-wave LDS ----
                #pragma unroll
                for (int r = 0; r < 4; ++r) {
                    float e0 = __expf(sa[r] - m4[r]);
                    float e1 = __expf(sb[r] - m4[r]);   // invalid tile -> 0
                    l4[r] += e0 + e1;
                    Pw[(quad * 4 + r) * PP + l15]      = f2bf(e0);
                    Pw[(quad * 4 + r) * PP + 16 + l15] = f2bf(e1);
                }
                // ---- PV ----
                bf16x8 pa = *(const bf16x8*)&Pw[l15 * PP + quad * 8];
                #pragma unroll
                for (int n = 0; n < 4; ++n) {
                    bf16x8 bv = *(const bf16x8*)&Vt[(n * 16 + l15) * VP + p * 32 + quad * 8];
                    o[n] = __builtin_amdgcn_mfma_f32_16x16x32_bf16(pa, bv, o[n], 0, 0, 0);
                }
            }
        }
        // ---- row-sum reduce + normalize + store ----
        #pragma unroll
        for (int d = 1; d < 16; d <<= 1) {
            #pragma unroll
            for (int r = 0; r < 4; ++r) l4[r] += __shfl_xor(l4[r], d, 64);
        }
        float rl4[4];
        #pragma unroll
        for (int r = 0; r < 4; ++r) rl4[r] = 1.f / l4[r];
        float* ob = out + ((size_t)b * TT + t0) * HH;
        #pragma unroll
        for (int n = 0; n < 4; ++n)
        #pragma unroll
        for (int r = 0; r < 4; ++r)
            ob[(quad * 4 + r) * HH + n * 16 + l15] = o[n][r] * rl4[r];
    }
}

extern "C" void kernel_launch(void* const* d_in, const int* in_sizes, int n_in,
                              void* d_out, int out_size, void* d_ws, size_t ws_size,
                              hipStream_t stream) {
    const float* x  = (const float*)d_in[0];
    const float* Wk = (const float*)d_in[1];
    const float* Wq = (const float*)d_in[2];
    const float* Wv = (const float*)d_in[3];
    const float* pe = (const float*)d_in[4];
    float* out = (float*)d_out;

    // ws: poskT[16384]f | posqT[16384]f | bias_sw[16384]float4-elems | W_sw[36864]u16
    float*  poskT  = (float*)d_ws;
    float*  posqT  = poskT + TT * HH;
    float4* biassw = (float4*)(posqT + TT * HH);
    u16*    W_sw   = (u16*)((float*)biassw + TT * TT);

    // one-time opt-in for >64K dynamic LDS (host-side, proven in R7)
    static bool attr_set = false;
    if (!attr_set) {
        hipFuncSetAttribute(reinterpret_cast<const void*>(fused_kernel),
                            hipFuncAttributeMaxDynamicSharedMemorySize, LDS_TOTAL);
        attr_set = true;
    }

    wprep_kernel<<<18, 256, 0, stream>>>(Wq, Wk, Wv, W_sw);
    pos_kernel<<<TT / 4, 256, 0, stream>>>(Wk, Wq, pe, poskT, posqT);
    bias_kernel<<<256, 64, 0, stream>>>(poskT, posqT, biassw);
    fused_kernel<<<BB, 512, LDS_TOTAL, stream>>>(x, W_sw, biassw, out);
}

// Round 9
// 200.457 us; speedup vs baseline: 1.2246x; 1.0031x over previous
//
#include <hip/hip_runtime.h>
#include <hip/hip_bf16.h>

typedef unsigned short u16;
typedef unsigned int u32;
using bf16x8 = __attribute__((ext_vector_type(8))) short;  // 8 bf16 (4 VGPRs)
using f32x4  = __attribute__((ext_vector_type(4))) float;  // 4 fp32

#define BB 512
#define TT 256
#define CC 192
#define HH 64

__device__ __forceinline__ u16 f2bf(float f) {
    __hip_bfloat16 h = __float2bfloat16(f);   // RNE
    u16 u; __builtin_memcpy(&u, &h, 2); return u;
}

// ================= prep kernels (unchanged) =================

// W_sw: B-fragment-swizzled weights. Frag fid = n3*6+ks (n3 = mat*4 + ntile, ks = K-step).
// lane (quad,l15) element u  =  W[c = ks*32+quad*8+u][h = (n3&3)*16+l15] of matrix n3>>2.
__global__ void wprep_kernel(const float* __restrict__ Wq,
                             const float* __restrict__ Wk,
                             const float* __restrict__ Wv,
                             u16* __restrict__ W_sw) {
    int gid  = blockIdx.x * 256 + threadIdx.x;   // 0..4607 (72 frags * 64 lanes)
    int fid  = gid >> 6, lane = gid & 63;
    int n3   = fid / 6,  ks   = fid % 6;
    int l15  = lane & 15, quad = lane >> 4;
    const float* W = (n3 < 4) ? Wq : (n3 < 8) ? Wk : Wv;
    const int h = (n3 & 3) * 16 + l15;
    u16* dst = W_sw + (size_t)gid * 8;
    #pragma unroll
    for (int u = 0; u < 8; ++u) {
        int c = ks * 32 + quad * 8 + u;
        dst[u] = f2bf(W[c * HH + h]);
    }
}

// poskT[h][t], posqT[h][t]
__global__ void pos_kernel(const float* __restrict__ Wk,
                           const float* __restrict__ Wq,
                           const float* __restrict__ pe,
                           float* __restrict__ poskT, float* __restrict__ posqT) {
    int t = blockIdx.x * 4 + (threadIdx.x >> 6);   // grid 64 x 256
    int h = threadIdx.x & 63;
    float ak = 0.f, aq = 0.f;
    for (int c = 0; c < CC; ++c) {
        float p = pe[t * CC + c];             // group-uniform broadcast
        ak += p * Wk[c * HH + h];             // coalesced
        aq += p * Wq[c * HH + h];
    }
    poskT[h * TT + t] = ak;
    posqT[h * TT + t] = aq;
}

// bias in C/D-fragment layout: bias_sw[(i*16+jt)*64 + lane] = float4 over r,
// component r = bias[row t0+quad*4+r][col jt*16+l15]  (only jt<=i written/read)
__global__ void bias_kernel(const float* __restrict__ poskT,
                            const float* __restrict__ posqT,
                            float4* __restrict__ bias_sw) {
    const int i = blockIdx.x >> 4, jt = blockIdx.x & 15;
    if (jt > i) return;
    const int lane = threadIdx.x;
    const int l15 = lane & 15, quad = lane >> 4;
    const int tq = i * 16 + quad * 4;     // query rows tq..tq+3
    const int jc = jt * 16 + l15;         // key col
    float s[4] = {0.f, 0.f, 0.f, 0.f};
    for (int h = 0; h < HH; ++h) {
        float pq = posqT[h * TT + jc];
        #pragma unroll
        for (int r = 0; r < 4; ++r)
            s[r] += poskT[h * TT + tq + r] * pq;
    }
    bias_sw[blockIdx.x * 64 + lane] = make_float4(s[0], s[1], s[2], s[3]);
}

// ================= fused kernel: QKV projection + flash attention ============
// v3 of the fused design: 1024 threads (16 waves -> 4/SIMD), dynamic LDS
// 124,928 B (same proven size as R8), 1 block/CU, grid 512 (2 rounds).
// Phase 1: 4 chunks x 64 rows. Wave (mh=w>>2, w4=w&3) computes m-tile mh,
// h-tile w4 (18 MFMA/chunk, acc[3]). T14 prefetch: chunk c+1's global loads
// issue before chunk c's MFMAs, ds_write after the barrier. Single X buffer.
// Phase 2: 16 waves <-> 16 i-tiles, one each; assignment balanced per SIMD
// (waves w%4==s share SIMD s; each SIMD's SumJ = 34).
// P buffer (16 x 1280 B) lives in the dead X region.

#define XP 200                           // X pitch (u16); 400 B rows
#define VP 264
#define PP 40
#define P_ELEMS 640                      // 16*40 u16 per wave
// LDS byte map (16B-aligned):
//   [0,      25600)  X stage (64 rows x 400 B)   /  P in phase 2 (16 x 1280 B)
//   [25600,  58368)  Q frags  (16 tiles x 2 x 1024 B)
//   [58368,  91136)  K frags
//   [91136, 124928)  V^T      (64 x VP u16)
#define Q_OFF 25600
#define K_OFF 58368
#define V_OFF 91136
#define LDS_TOTAL 124928

__global__ __launch_bounds__(1024, 1)
void fused_kernel(const float* __restrict__ x,
                  const u16* __restrict__ W_sw,
                  const float4* __restrict__ bias_sw,
                  float* __restrict__ out) {
    extern __shared__ __align__(16) char smem[];
    u16* Qlds = (u16*)(smem + Q_OFF);
    u16* Klds = (u16*)(smem + K_OFF);
    u16* Vt   = (u16*)(smem + V_OFF);

    const int tid  = threadIdx.x;
    const int w    = tid >> 6;           // 0..15
    const int w4   = w & 3;              // h-tile
    const int mh   = w >> 2;             // m-tile within 64-row chunk
    const int lane = tid & 63;
    const int l15  = lane & 15;
    const int quad = lane >> 4;
    const int b    = blockIdx.x;

    // ---- hoist W fragments for h-tile w4 (compiler may sink under pressure;
    //      at 4 waves/SIMD the L2 reload latency is TLP-hidden either way) ----
    const bf16x8* Wv8 = (const bf16x8*)W_sw;
    bf16x8 Wf[18];                              // [mat][ks], mat: 0=Q 1=K 2=V
    #pragma unroll
    for (int mat = 0; mat < 3; ++mat)
        #pragma unroll
        for (int ks = 0; ks < 6; ++ks)
            Wf[mat * 6 + ks] = Wv8[(((mat * 4 + w4) * 6) + ks) * 64 + lane];

    // ================= phase 1: projection (4 chunks x 64 rows) =============
    const int hs    = w4 >> 1;
    const int quadp = (w4 * 2 + (l15 >> 3)) & 3;
    const int uu    = l15 & 7;

    // prologue: stage chunk 0
    {
        const float* xb = x + (size_t)b * TT * CC;
        float4 vv[3];
        #pragma unroll
        for (int it = 0; it < 3; ++it)
            vv[it] = *(const float4*)(xb + (it * 1024 + tid) * 4);
        u16* xs = (u16*)smem;
        #pragma unroll
        for (int it = 0; it < 3; ++it) {
            const int flat = (it * 1024 + tid) * 4;       // 0..12287
            const int row = flat / CC, col = flat % CC;   // CC%4==0: no row cross
            uint2 pk;
            pk.x = (u32)f2bf(vv[it].x) | ((u32)f2bf(vv[it].y) << 16);
            pk.y = (u32)f2bf(vv[it].z) | ((u32)f2bf(vv[it].w) << 16);
            *(uint2*)&xs[row * XP + col] = pk;
        }
    }
    __syncthreads();

    #pragma unroll 1
    for (int c4 = 0; c4 < 4; ++c4) {
        const bool hn = (c4 < 3);
        // ---- issue next chunk's global loads FIRST (hide under MFMAs) ----
        float4 vnext[3];
        if (hn) {
            const float* xb = x + ((size_t)b * TT + (c4 + 1) * 64) * CC;
            #pragma unroll
            for (int it = 0; it < 3; ++it)
                vnext[it] = *(const float4*)(xb + (it * 1024 + tid) * 4);
        }
        // ---- compute from xs ----
        const u16* xs = (const u16*)smem;
        f32x4 acc[3];
        #pragma unroll
        for (int i = 0; i < 3; ++i) acc[i] = {0.f, 0.f, 0.f, 0.f};
        #pragma unroll
        for (int ks = 0; ks < 6; ++ks) {
            const bf16x8 a = *(const bf16x8*)&xs[(mh * 16 + l15) * XP + ks * 32 + quad * 8];
            #pragma unroll
            for (int mat = 0; mat < 3; ++mat)
                acc[mat] = __builtin_amdgcn_mfma_f32_16x16x32_bf16(
                    a, Wf[mat * 6 + ks], acc[mat], 0, 0, 0);
        }
        // ---- epilogue: Q/K frags + V^T into LDS ----
        {
            const int i_loc = c4 * 4 + mh;                 // t-tile 0..15
            const int base  = (i_loc * 2 + hs) * 512 + (quadp * 16 + quad * 4) * 8 + uu;
            #pragma unroll
            for (int r = 0; r < 4; ++r) {
                Qlds[base + r * 8] = f2bf(acc[0][r]);      // A-frag layout
                Klds[base + r * 8] = f2bf(acc[1][r]);      // B-frag layout
            }
            #pragma unroll
            for (int r = 0; r < 4; ++r)
                Vt[(w4 * 16 + l15) * VP + i_loc * 16 + quad * 4 + r]
                    = f2bf(acc[2][r]);                     // V^T[h][t]
        }
        __syncthreads();   // xs readers done; epilogue visible (last iter:
                           // doubles as the proj->attn barrier)
        if (hn) {
            u16* xsn = (u16*)smem;
            #pragma unroll
            for (int it = 0; it < 3; ++it) {
                const int flat = (it * 1024 + tid) * 4;
                const int row = flat / CC, col = flat % CC;
                uint2 pk;
                pk.x = (u32)f2bf(vnext[it].x) | ((u32)f2bf(vnext[it].y) << 16);
                pk.y = (u32)f2bf(vnext[it].z) | ((u32)f2bf(vnext[it].w) << 16);
                *(uint2*)&xsn[row * XP + col] = pk;
            }
            __syncthreads();   // next chunk staged
        }
    }

    // ================= phase 2: attention (one i-tile per wave) =============
    u16* Pw = (u16*)smem + w * P_ELEMS;         // X region is dead now (20.5 KB)
    const float scale = 0.07216878364870322f;  // 192^-0.5
    const f32x4 zero4 = {0.f, 0.f, 0.f, 0.f};
    const bf16x8* qv = (const bf16x8*)Qlds;
    const bf16x8* kv = (const bf16x8*)Klds;

    // per-SIMD balanced tile assignment: s = w&3 (SIMD), j = w>>2
    // SIMD s gets tiles {2s, 15-2s, 2s+1, 14-2s} -> SumJ = 34 each
    const int s2 = w & 3, j2 = w >> 2;
    const int i  = (j2 & 1) ? (15 - 2 * s2 - (j2 >> 1)) : (2 * s2 + (j2 >> 1));
    const int t0 = 16 * i;
    const int J  = i + 1;
    const int Pq = (J + 1) >> 1;

    const bf16x8 qf0 = qv[(i * 2 + 0) * 64 + lane];
    const bf16x8 qf1 = qv[(i * 2 + 1) * 64 + lane];

    f32x4 o[4];
    float m4[4], l4[4];
    #pragma unroll
    for (int n = 0; n < 4; ++n) o[n] = zero4;
    #pragma unroll
    for (int r = 0; r < 4; ++r) { m4[r] = -1e30f; l4[r] = 0.f; }

    #pragma unroll
    for (int p = 0; p < 8; ++p) {
        if (p < Pq) {
            const int jt0 = 2 * p, jt1 = 2 * p + 1;
            // ---- S tiles (pair) ----
            f32x4 sa = zero4, sb;
            {
                bf16x8 k0 = kv[(jt0 * 2 + 0) * 64 + lane];
                bf16x8 k1 = kv[(jt0 * 2 + 1) * 64 + lane];
                sa = __builtin_amdgcn_mfma_f32_16x16x32_bf16(qf0, k0, sa, 0, 0, 0);
                sa = __builtin_amdgcn_mfma_f32_16x16x32_bf16(qf1, k1, sa, 0, 0, 0);
                const float4 b4 = bias_sw[(i * 16 + jt0) * 64 + lane];
                sa[0] = sa[0] * scale + b4.x;
                sa[1] = sa[1] * scale + b4.y;
                sa[2] = sa[2] * scale + b4.z;
                sa[3] = sa[3] * scale + b4.w;
                if (jt0 == i) {
                    #pragma unroll
                    for (int r = 0; r < 4; ++r)
                        if (l15 > quad * 4 + r) sa[r] = -1e30f;
                }
            }
            if (jt1 < J) {
                sb = zero4;
                bf16x8 k0 = kv[(jt1 * 2 + 0) * 64 + lane];
                bf16x8 k1 = kv[(jt1 * 2 + 1) * 64 + lane];
                sb = __builtin_amdgcn_mfma_f32_16x16x32_bf16(qf0, k0, sb, 0, 0, 0);
                sb = __builtin_amdgcn_mfma_f32_16x16x32_bf16(qf1, k1, sb, 0, 0, 0);
                const float4 b4 = bias_sw[(i * 16 + jt1) * 64 + lane];
                sb[0] = sb[0] * scale + b4.x;
                sb[1] = sb[1] * scale + b4.y;
                sb[2] = sb[2] * scale + b4.z;
                sb[3] = sb[3] * scale + b4.w;
                if (jt1 == i) {
                    #pragma unroll
                    for (int r = 0; r < 4; ++r)
                        if (l15 > quad * 4 + r) sb[r] = -1e30f;
                }
            } else {
                sb[0] = -1e30f; sb[1] = -1e30f; sb[2] = -1e30f; sb[3] = -1e30f;
            }
            // ---- pair row max (16-lane group shares rows) ----
            float t4[4];
            #pragma unroll
            for (int r = 0; r < 4; ++r) t4[r] = fmaxf(sa[r], sb[r]);
            #pragma unroll
            for (int d = 1; d < 16; d <<= 1) {
                #pragma unroll
                for (int r = 0; r < 4; ++r) t4[r] = fmaxf(t4[r], __shfl_xor(t4[r], d, 64));
            }
            // ---- online rescale ----
            float al[4];
            #pragma unroll
            for (int r = 0; r < 4; ++r) {
                float mn = fmaxf(m4[r], t4[r]);
                al[r] = __expf(m4[r] - mn);   // first pair: exp(-huge)=0
                m4[r] = mn;
                l4[r] *= al[r];
            }
            #pragma unroll
            for (int n = 0; n < 4; ++n)
            #pragma unroll
            for (int r = 0; r < 4; ++r) o[n][r] *= al[r];
            // ---- exp + P -> per-wave LDS ----
            #pragma unroll
            for (int r = 0; r < 4; ++r) {
                float e0 = __expf(sa[r] - m4[r]);
                float e1 = __expf(sb[r] - m4[r]);   // invalid tile -> 0
                l4[r] += e0 + e1;
                Pw[(quad * 4 + r) * PP + l15]      = f2bf(e0);
                Pw[(quad * 4 + r) * PP + 16 + l15] = f2bf(e1);
            }
            // ---- PV ----
            bf16x8 pa = *(const bf16x8*)&Pw[l15 * PP + quad * 8];
            #pragma unroll
            for (int n = 0; n < 4; ++n) {
                bf16x8 bv = *(const bf16x8*)&Vt[(n * 16 + l15) * VP + p * 32 + quad * 8];
                o[n] = __builtin_amdgcn_mfma_f32_16x16x32_bf16(pa, bv, o[n], 0, 0, 0);
            }
        }
    }
    // ---- row-sum reduce + normalize + store ----
    #pragma unroll
    for (int d = 1; d < 16; d <<= 1) {
        #pragma unroll
        for (int r = 0; r < 4; ++r) l4[r] += __shfl_xor(l4[r], d, 64);
    }
    float rl4[4];
    #pragma unroll
    for (int r = 0; r < 4; ++r) rl4[r] = 1.f / l4[r];
    float* ob = out + ((size_t)b * TT + t0) * HH;
    #pragma unroll
    for (int n = 0; n < 4; ++n)
    #pragma unroll
    for (int r = 0; r < 4; ++r)
        ob[(quad * 4 + r) * HH + n * 16 + l15] = o[n][r] * rl4[r];
}

extern "C" void kernel_launch(void* const* d_in, const int* in_sizes, int n_in,
                              void* d_out, int out_size, void* d_ws, size_t ws_size,
                              hipStream_t stream) {
    const float* x  = (const float*)d_in[0];
    const float* Wk = (const float*)d_in[1];
    const float* Wq = (const float*)d_in[2];
    const float* Wv = (const float*)d_in[3];
    const float* pe = (const float*)d_in[4];
    float* out = (float*)d_out;

    // ws: poskT[16384]f | posqT[16384]f | bias_sw[16384]float4-elems | W_sw[36864]u16
    float*  poskT  = (float*)d_ws;
    float*  posqT  = poskT + TT * HH;
    float4* biassw = (float4*)(posqT + TT * HH);
    u16*    W_sw   = (u16*)((float*)biassw + TT * TT);

    // one-time opt-in for >64K dynamic LDS (host-side, proven in R7/R8)
    static bool attr_set = false;
    if (!attr_set) {
        hipFuncSetAttribute(reinterpret_cast<const void*>(fused_kernel),
                            hipFuncAttributeMaxDynamicSharedMemorySize, LDS_TOTAL);
        attr_set = true;
    }

    wprep_kernel<<<18, 256, 0, stream>>>(Wq, Wk, Wv, W_sw);
    pos_kernel<<<TT / 4, 256, 0, stream>>>(Wk, Wq, pe, poskT, posqT);
    bias_kernel<<<256, 64, 0, stream>>>(poskT, posqT, biassw);
    fused_kernel<<<BB, 1024, LDS_TOTAL, stream>>>(x, W_sw, biassw, out);
}